// Round 6
// baseline (321.916 us; speedup 1.0000x reference)
//
#include <hip/hip_runtime.h>
#include <hip/hip_bf16.h>

#define BATCH 4
#define NSEQ  4096
#define CDIM  256
#define CQK   32
#define L2E   1.44269504088896340736f

typedef short bf16x8 __attribute__((ext_vector_type(8)));   // 8 bf16 in 4 VGPRs
typedef float f32x16 __attribute__((ext_vector_type(16)));
typedef unsigned short u16;
typedef unsigned int   u32;
typedef unsigned int   u32x4 __attribute__((ext_vector_type(4)));

__device__ __forceinline__ u32 pk2(float lo, float hi) {    // compiler fuses to v_cvt_pk_bf16_f32
  u16 a = __builtin_bit_cast(u16, __float2bfloat16(lo));
  u16 b = __builtin_bit_cast(u16, __float2bfloat16(hi));
  return (u32)a | ((u32)b << 16);
}
__device__ __forceinline__ bf16x8 ld8(const u16* p) {
  uint4 u = *(const uint4*)p;
  return __builtin_bit_cast(bf16x8, u);
}

// ---------------- projection kernel: hT (bf16 [B][256][4096]), f,g (bf16 [B*N][32]) ------
// f is pre-scaled by log2(e) so attention can use exp2 directly.
__global__ __launch_bounds__(256) void proj_kernel(
    const float* __restrict__ x,
    const float* __restrict__ Wf, const float* __restrict__ bf,
    const float* __restrict__ Wg, const float* __restrict__ bg,
    const float* __restrict__ Wh, const float* __restrict__ bh,
    u16* __restrict__ f_ws, u16* __restrict__ g_ws, u16* __restrict__ hT_ws) {
  __shared__ float xs[16][260];                 // +4 pad: conflict-free strided reads
  const int tid  = threadIdx.x;
  const int row0 = blockIdx.x * 16;             // global row in [0,16384)

  { // stage 16 rows of x
    const int r = tid >> 4, j = tid & 15;
    const float4* xg = (const float4*)(x + ((size_t)row0 + r) * CDIM);
#pragma unroll
    for (int t = 0; t < 4; ++t)
      *(float4*)&xs[r][(j + t * 16) * 4] = xg[j + t * 16];
  }
  __syncthreads();

  { // f and g: thread (rr,c) does rows rr and rr+8, column c
    const int c = tid & 31, rr = tid >> 5;
    float af0 = bf[c], af1 = bf[c], ag0 = bg[c], ag1 = bg[c];
    for (int k = 0; k < CDIM; ++k) {
      float wf = Wf[k * CQK + c], wg = Wg[k * CQK + c];
      float x0 = xs[rr][k], x1 = xs[rr + 8][k];
      af0 = fmaf(x0, wf, af0); af1 = fmaf(x1, wf, af1);
      ag0 = fmaf(x0, wg, ag0); ag1 = fmaf(x1, wg, ag1);
    }
    f_ws[((size_t)row0 + rr)     * CQK + c] = (u16)(pk2(af0 * L2E, 0.f) & 0xFFFF);
    f_ws[((size_t)row0 + rr + 8) * CQK + c] = (u16)(pk2(af1 * L2E, 0.f) & 0xFFFF);
    g_ws[((size_t)row0 + rr)     * CQK + c] = (u16)(pk2(ag0, 0.f) & 0xFFFF);
    g_ws[((size_t)row0 + rr + 8) * CQK + c] = (u16)(pk2(ag1, 0.f) & 0xFFFF);
  }

  { // h: thread = output channel c; 16 rows; store transposed
    const int c = tid;
    float acc[16];
#pragma unroll
    for (int r = 0; r < 16; ++r) acc[r] = bh[c];
    for (int k = 0; k < CDIM; ++k) {
      float wk = Wh[k * CDIM + c];
#pragma unroll
      for (int r = 0; r < 16; ++r) acc[r] = fmaf(xs[r][k], wk, acc[r]);
    }
    const int b = row0 >> 12, n0 = row0 & (NSEQ - 1);
    u16* dst = hT_ws + ((size_t)b * CDIM + c) * NSEQ + n0;
    uint4 w0 = make_uint4(pk2(acc[0], acc[1]),  pk2(acc[2], acc[3]),
                          pk2(acc[4], acc[5]),  pk2(acc[6], acc[7]));
    uint4 w1 = make_uint4(pk2(acc[8], acc[9]),  pk2(acc[10], acc[11]),
                          pk2(acc[12], acc[13]), pk2(acc[14], acc[15]));
    *(uint4*)dst = w0;
    *(uint4*)(dst + 8) = w1;
  }
}

// ---------------- flash attention: 8 waves = 2 key-splits x 4 channel-groups -------------
// wave = 32 query rows x 64 channels x 2048 keys. mfma_f32_32x32x16_bf16 layouts:
//   A[row=l&31][k=(l>>5)*8+i], B[k=(l>>5)*8+i][col=l&31],
//   D[row=(r&3)+8*(r>>2)+4*(l>>5)][col=l&31]
// No-max softmax => split partials are ADDITIVE: O=O0+O1, l=l0+l1 (LDS exchange, no HBM).
__global__ __launch_bounds__(512, 6) void attn_kernel(
    const float* __restrict__ x, const float* __restrict__ gamma_p,
    const u16* __restrict__ f_ws, const u16* __restrict__ g_ws,
    const u16* __restrict__ hT_ws, float* __restrict__ out) {
  __shared__ u32   ols[4][64][17];              // bf16-pair O exchange; stride 17: conflict-free
  __shared__ float lsh[64];

  const int tid   = threadIdx.x;
  const int lan   = tid & 63;
  const int lan31 = lan & 31;
  const int g2    = lan >> 5;
  const int w     = tid >> 6;                   // wave id 0..7
  const int sid   = w >> 2;                     // key-split 0/1
  const int cw    = (w & 3) * 64;               // channel-group offset
  // XCD-aware swizzle: batch b pinned to XCDs {2b, 2b+1}
  const int bid   = blockIdx.x;
  const int xcd   = bid & 7;
  const int b     = xcd >> 1;
  const int n0    = (((xcd & 1) << 6) | (bid >> 3)) * 32;

  const float gamma = gamma_p[0];

  // query fragments (resident): B[k][n]=g[n][k]
  const u16* gp = g_ws + ((size_t)b * NSEQ + n0 + lan31) * CQK + g2 * 8;
  bf16x8 bg0 = ld8(gp);                         // k 0..15
  bf16x8 bg1 = ld8(gp + 16);                    // k 16..31

  f32x16 o0, o1, zfrag;
#pragma unroll
  for (int r = 0; r < 16; ++r) { o0[r] = 0.f; o1[r] = 0.f; zfrag[r] = 0.f; }
  float l_run = 0.f;

  const u16* fbase = f_ws  + ((size_t)b * NSEQ + sid * 2048 + lan31) * CQK + g2 * 8;
  const u16* hbase = hT_ws + ((size_t)b * CDIM + cw + lan31) * NSEQ + sid * 2048 + g2 * 8;

  // prologue loads (first chunk of this split); prefetch pointers at chunk+1
  bf16x8 af0 = ld8(fbase), af1 = ld8(fbase + 16);
  bf16x8 h00 = ld8(hbase),                      h01 = ld8(hbase + 16);
  bf16x8 h10 = ld8(hbase + (size_t)32 * NSEQ),  h11 = ld8(hbase + (size_t)32 * NSEQ + 16);
  const u16* fp = fbase + 32 * CQK;
  const u16* hp = hbase + 32;

#pragma unroll 2
  for (int it = 0; it < 2048 / 32; ++it) {
    // S^T = f . g^T : lane holds 16 key-scores (log2 domain) for query col n
    f32x16 s = __builtin_amdgcn_mfma_f32_32x32x16_bf16(af0, bg0, zfrag, 0, 0, 0);
    s        = __builtin_amdgcn_mfma_f32_32x32x16_bf16(af1, bg1, s,     0, 0, 0);

    // prefetch next chunk (overruns land in following ws region / neighbor split data)
    bf16x8 naf0 = ld8(fp), naf1 = ld8(fp + 16);
    bf16x8 nh00 = ld8(hp), nh01 = ld8(hp + 16);
    bf16x8 nh10 = ld8(hp + (size_t)32 * NSEQ), nh11 = ld8(hp + (size_t)32 * NSEQ + 16);
    fp += 32 * CQK;
    hp += 32;

    // p = exp2(s); no max tracking (scores bounded; f32 range ample)
    float p[16];
#pragma unroll
    for (int r = 0; r < 16; ++r) p[r] = exp2f(s[r]);

    float t0 = (p[0] + p[1]) + (p[2] + p[3]);
    float t1 = (p[4] + p[5]) + (p[6] + p[7]);
    float t2 = (p[8] + p[9]) + (p[10] + p[11]);
    float t3 = (p[12] + p[13]) + (p[14] + p[15]);
    float rs = (t0 + t1) + (t2 + t3);
    auto rr = __builtin_amdgcn_permlane32_swap(__builtin_bit_cast(u32, rs),
                                               __builtin_bit_cast(u32, rs), false, false);
    l_run += __builtin_bit_cast(float, (u32)rr[0]) + __builtin_bit_cast(float, (u32)rr[1]);

    // pack P quads: quad q holds keys m = 8q + 4*g2 .. +3
    u32 q0a = pk2(p[0],  p[1]),  q0b = pk2(p[2],  p[3]);
    u32 q1a = pk2(p[4],  p[5]),  q1b = pk2(p[6],  p[7]);
    u32 q2a = pk2(p[8],  p[9]),  q2b = pk2(p[10], p[11]);
    u32 q3a = pk2(p[12], p[13]), q3b = pk2(p[14], p[15]);

    // permlane32_swap(q[2k]a, q[2k+1]a) = {A reg0, A reg2} of PV k-step k (verified map)
    auto r02a = __builtin_amdgcn_permlane32_swap(q0a, q1a, false, false);
    auto r13a = __builtin_amdgcn_permlane32_swap(q0b, q1b, false, false);
    auto r02b = __builtin_amdgcn_permlane32_swap(q2a, q3a, false, false);
    auto r13b = __builtin_amdgcn_permlane32_swap(q2b, q3b, false, false);
    u32x4 apu0 = {(u32)r02a[0], (u32)r13a[0], (u32)r02a[1], (u32)r13a[1]};
    u32x4 apu1 = {(u32)r02b[0], (u32)r13b[0], (u32)r02b[1], (u32)r13b[1]};
    bf16x8 ap0 = __builtin_bit_cast(bf16x8, apu0);
    bf16x8 ap1 = __builtin_bit_cast(bf16x8, apu1);

    // O += P . h
    o0 = __builtin_amdgcn_mfma_f32_32x32x16_bf16(ap0, h00, o0, 0, 0, 0);
    o0 = __builtin_amdgcn_mfma_f32_32x32x16_bf16(ap1, h01, o0, 0, 0, 0);
    o1 = __builtin_amdgcn_mfma_f32_32x32x16_bf16(ap0, h10, o1, 0, 0, 0);
    o1 = __builtin_amdgcn_mfma_f32_32x32x16_bf16(ap1, h11, o1, 0, 0, 0);

    af0 = naf0; af1 = naf1;
    h00 = nh00; h01 = nh01; h10 = nh10; h11 = nh11;
  }

  // ---- split combine: sid1 hands O (bf16 pairs) + l to sid0 via LDS ----
  if (sid) {
    u32* dst = &ols[w & 3][lan][0];
#pragma unroll
    for (int r = 0; r < 16; ++r) dst[r] = pk2(o0[r], o1[r]);
    if ((w & 3) == 0) lsh[lan] = l_run;
  }
  __syncthreads();
  if (sid) return;

  const u32* src = &ols[w & 3][lan][0];
#pragma unroll
  for (int r = 0; r < 16; ++r) {
    u32 v = src[r];
    o0[r] += __builtin_bit_cast(float, v << 16);
    o1[r] += __builtin_bit_cast(float, v & 0xFFFF0000u);
  }
  const float l_tot = l_run + lsh[lan];

  // epilogue: y = gamma * O / l + x
  const float gi = gamma / l_tot;
#pragma unroll
  for (int r = 0; r < 16; ++r) {
    const int nl = (r & 3) + 8 * (r >> 2) + 4 * g2;     // query row of this acc reg
    const float gir = __shfl(gi, nl);
    const size_t row = (size_t)b * NSEQ + n0 + nl;
    const size_t i0 = row * CDIM + cw + lan31;
    out[i0]      = fmaf(gir, o0[r], x[i0]);
    out[i0 + 32] = fmaf(gir, o1[r], x[i0 + 32]);
  }
}

extern "C" void kernel_launch(void* const* d_in, const int* in_sizes, int n_in,
                              void* d_out, int out_size, void* d_ws, size_t ws_size,
                              hipStream_t stream) {
  const float* x     = (const float*)d_in[0];
  const float* Wf    = (const float*)d_in[1];
  const float* bf    = (const float*)d_in[2];
  const float* Wg    = (const float*)d_in[3];
  const float* bg    = (const float*)d_in[4];
  const float* Wh    = (const float*)d_in[5];
  const float* bh    = (const float*)d_in[6];
  const float* gamma = (const float*)d_in[7];
  float* out = (float*)d_out;

  // layout: hT first so prefetch overruns land in f/g (in-bounds)
  u16* hT_ws = (u16*)d_ws;                                   // 8 MB
  u16* f_ws  = hT_ws + (size_t)BATCH * CDIM * NSEQ;          // 1 MB
  u16* g_ws  = f_ws  + (size_t)BATCH * NSEQ * CQK;           // 1 MB

  hipLaunchKernelGGL(proj_kernel, dim3(1024), dim3(256), 0, stream,
                     x, Wf, bf, Wg, bg, Wh, bh, f_ws, g_ws, hT_ws);
  hipLaunchKernelGGL(attn_kernel, dim3(512), dim3(512), 0, stream,
                     x, gamma, f_ws, g_ws, hT_ws, out);
}

// Round 8
// 209.998 us; speedup vs baseline: 1.5329x; 1.5329x over previous
//
#include <hip/hip_runtime.h>
#include <hip/hip_bf16.h>

#define BATCH 4
#define NSEQ  4096
#define CDIM  256
#define CQK   32
#define L2E   1.44269504088896340736f

typedef short bf16x8 __attribute__((ext_vector_type(8)));   // 8 bf16 in 4 VGPRs
typedef float f32x16 __attribute__((ext_vector_type(16)));
typedef unsigned short u16;
typedef unsigned int   u32;
typedef unsigned int   u32x4 __attribute__((ext_vector_type(4)));

__device__ __forceinline__ u32 pk2(float lo, float hi) {    // compiler fuses to v_cvt_pk_bf16_f32
  u16 a = __builtin_bit_cast(u16, __float2bfloat16(lo));
  u16 b = __builtin_bit_cast(u16, __float2bfloat16(hi));
  return (u32)a | ((u32)b << 16);
}
__device__ __forceinline__ bf16x8 ld8(const u16* p) {
  uint4 u = *(const uint4*)p;
  return __builtin_bit_cast(bf16x8, u);
}

// ---------------- projection kernel: hT (bf16 [B][256][4096]), f,g (bf16 [B*N][32]) ------
// f is pre-scaled by log2(e) so attention can use exp2 directly.
__global__ __launch_bounds__(256) void proj_kernel(
    const float* __restrict__ x,
    const float* __restrict__ Wf, const float* __restrict__ bf,
    const float* __restrict__ Wg, const float* __restrict__ bg,
    const float* __restrict__ Wh, const float* __restrict__ bh,
    u16* __restrict__ f_ws, u16* __restrict__ g_ws, u16* __restrict__ hT_ws) {
  __shared__ float xs[16][260];                 // +4 pad: conflict-free strided reads
  const int tid  = threadIdx.x;
  const int row0 = blockIdx.x * 16;             // global row in [0,16384)

  { // stage 16 rows of x
    const int r = tid >> 4, j = tid & 15;
    const float4* xg = (const float4*)(x + ((size_t)row0 + r) * CDIM);
#pragma unroll
    for (int t = 0; t < 4; ++t)
      *(float4*)&xs[r][(j + t * 16) * 4] = xg[j + t * 16];
  }
  __syncthreads();

  { // f and g: thread (rr,c) does rows rr and rr+8, column c
    const int c = tid & 31, rr = tid >> 5;
    float af0 = bf[c], af1 = bf[c], ag0 = bg[c], ag1 = bg[c];
    for (int k = 0; k < CDIM; ++k) {
      float wf = Wf[k * CQK + c], wg = Wg[k * CQK + c];
      float x0 = xs[rr][k], x1 = xs[rr + 8][k];
      af0 = fmaf(x0, wf, af0); af1 = fmaf(x1, wf, af1);
      ag0 = fmaf(x0, wg, ag0); ag1 = fmaf(x1, wg, ag1);
    }
    f_ws[((size_t)row0 + rr)     * CQK + c] = (u16)(pk2(af0 * L2E, 0.f) & 0xFFFF);
    f_ws[((size_t)row0 + rr + 8) * CQK + c] = (u16)(pk2(af1 * L2E, 0.f) & 0xFFFF);
    g_ws[((size_t)row0 + rr)     * CQK + c] = (u16)(pk2(ag0, 0.f) & 0xFFFF);
    g_ws[((size_t)row0 + rr + 8) * CQK + c] = (u16)(pk2(ag1, 0.f) & 0xFFFF);
  }

  { // h: thread = output channel c; 16 rows; store transposed
    const int c = tid;
    float acc[16];
#pragma unroll
    for (int r = 0; r < 16; ++r) acc[r] = bh[c];
    for (int k = 0; k < CDIM; ++k) {
      float wk = Wh[k * CDIM + c];
#pragma unroll
      for (int r = 0; r < 16; ++r) acc[r] = fmaf(xs[r][k], wk, acc[r]);
    }
    const int b = row0 >> 12, n0 = row0 & (NSEQ - 1);
    u16* dst = hT_ws + ((size_t)b * CDIM + c) * NSEQ + n0;
    uint4 w0 = make_uint4(pk2(acc[0], acc[1]),  pk2(acc[2], acc[3]),
                          pk2(acc[4], acc[5]),  pk2(acc[6], acc[7]));
    uint4 w1 = make_uint4(pk2(acc[8], acc[9]),  pk2(acc[10], acc[11]),
                          pk2(acc[12], acc[13]), pk2(acc[14], acc[15]));
    *(uint4*)dst = w0;
    *(uint4*)(dst + 8) = w1;
  }
}

// ---------------- flash attention: 8 waves = 2 key-splits x 4 channel-groups -------------
// wave = 32 query rows x 64 channels x 2048 keys. mfma_f32_32x32x16_bf16 layouts:
//   A[row=l&31][k=(l>>5)*8+i], B[k=(l>>5)*8+i][col=l&31],
//   D[row=(r&3)+8*(r>>2)+4*(l>>5)][col=l&31]
// No-max softmax => split partials are ADDITIVE: O=O0+O1, l=l0+l1 (LDS exchange, no HBM).
// launch_bounds(512,4): 4 waves/SIMD cap -> 128 regs/wave, NO spill (6 caused 400MB scratch).
__global__ __launch_bounds__(512, 4) void attn_kernel(
    const float* __restrict__ x, const float* __restrict__ gamma_p,
    const u16* __restrict__ f_ws, const u16* __restrict__ g_ws,
    const u16* __restrict__ hT_ws, float* __restrict__ out) {
  __shared__ u32   ols[4][64][17];              // bf16-pair O exchange; stride 17: conflict-free
  __shared__ float lsh[64];

  const int tid   = threadIdx.x;
  const int lan   = tid & 63;
  const int lan31 = lan & 31;
  const int g2    = lan >> 5;
  const int w     = tid >> 6;                   // wave id 0..7
  const int sid   = w >> 2;                     // key-split 0/1
  const int cw    = (w & 3) * 64;               // channel-group offset
  // XCD-aware swizzle: batch b pinned to XCDs {2b, 2b+1}
  const int bid   = blockIdx.x;
  const int xcd   = bid & 7;
  const int b     = xcd >> 1;
  const int n0    = (((xcd & 1) << 6) | (bid >> 3)) * 32;

  const float gamma = gamma_p[0];

  // query fragments (resident): B[k][n]=g[n][k]
  const u16* gp = g_ws + ((size_t)b * NSEQ + n0 + lan31) * CQK + g2 * 8;
  bf16x8 bg0 = ld8(gp);                         // k 0..15
  bf16x8 bg1 = ld8(gp + 16);                    // k 16..31

  f32x16 o0, o1, zfrag;
#pragma unroll
  for (int r = 0; r < 16; ++r) { o0[r] = 0.f; o1[r] = 0.f; zfrag[r] = 0.f; }
  float l_run = 0.f;

  const u16* fbase = f_ws  + ((size_t)b * NSEQ + sid * 2048 + lan31) * CQK + g2 * 8;
  const u16* hbase = hT_ws + ((size_t)b * CDIM + cw + lan31) * NSEQ + sid * 2048 + g2 * 8;

  // prologue loads (first chunk of this split); prefetch pointers at chunk+1
  bf16x8 af0 = ld8(fbase), af1 = ld8(fbase + 16);
  bf16x8 h00 = ld8(hbase),                      h01 = ld8(hbase + 16);
  bf16x8 h10 = ld8(hbase + (size_t)32 * NSEQ),  h11 = ld8(hbase + (size_t)32 * NSEQ + 16);
  const u16* fp = fbase + 32 * CQK;
  const u16* hp = hbase + 32;

#pragma unroll 2
  for (int it = 0; it < 2048 / 32; ++it) {
    // S^T = f . g^T : lane holds 16 key-scores (log2 domain) for query col n
    f32x16 s = __builtin_amdgcn_mfma_f32_32x32x16_bf16(af0, bg0, zfrag, 0, 0, 0);
    s        = __builtin_amdgcn_mfma_f32_32x32x16_bf16(af1, bg1, s,     0, 0, 0);

    // prefetch next chunk (overruns land in following ws region / neighbor split data)
    bf16x8 naf0 = ld8(fp), naf1 = ld8(fp + 16);
    bf16x8 nh00 = ld8(hp), nh01 = ld8(hp + 16);
    bf16x8 nh10 = ld8(hp + (size_t)32 * NSEQ), nh11 = ld8(hp + (size_t)32 * NSEQ + 16);
    fp += 32 * CQK;
    hp += 32;

    // p = exp2(s); no max tracking (scores bounded; f32 range ample)
    float p[16];
#pragma unroll
    for (int r = 0; r < 16; ++r) p[r] = exp2f(s[r]);

    float t0 = (p[0] + p[1]) + (p[2] + p[3]);
    float t1 = (p[4] + p[5]) + (p[6] + p[7]);
    float t2 = (p[8] + p[9]) + (p[10] + p[11]);
    float t3 = (p[12] + p[13]) + (p[14] + p[15]);
    float rs = (t0 + t1) + (t2 + t3);
    auto rr = __builtin_amdgcn_permlane32_swap(__builtin_bit_cast(u32, rs),
                                               __builtin_bit_cast(u32, rs), false, false);
    l_run += __builtin_bit_cast(float, (u32)rr[0]) + __builtin_bit_cast(float, (u32)rr[1]);

    // pack P quads: quad q holds keys m = 8q + 4*g2 .. +3
    u32 q0a = pk2(p[0],  p[1]),  q0b = pk2(p[2],  p[3]);
    u32 q1a = pk2(p[4],  p[5]),  q1b = pk2(p[6],  p[7]);
    u32 q2a = pk2(p[8],  p[9]),  q2b = pk2(p[10], p[11]);
    u32 q3a = pk2(p[12], p[13]), q3b = pk2(p[14], p[15]);

    // permlane32_swap(q[2k]a, q[2k+1]a) = {A reg0, A reg2} of PV k-step k (verified map)
    auto r02a = __builtin_amdgcn_permlane32_swap(q0a, q1a, false, false);
    auto r13a = __builtin_amdgcn_permlane32_swap(q0b, q1b, false, false);
    auto r02b = __builtin_amdgcn_permlane32_swap(q2a, q3a, false, false);
    auto r13b = __builtin_amdgcn_permlane32_swap(q2b, q3b, false, false);
    u32x4 apu0 = {(u32)r02a[0], (u32)r13a[0], (u32)r02a[1], (u32)r13a[1]};
    u32x4 apu1 = {(u32)r02b[0], (u32)r13b[0], (u32)r02b[1], (u32)r13b[1]};
    bf16x8 ap0 = __builtin_bit_cast(bf16x8, apu0);
    bf16x8 ap1 = __builtin_bit_cast(bf16x8, apu1);

    // O += P . h
    o0 = __builtin_amdgcn_mfma_f32_32x32x16_bf16(ap0, h00, o0, 0, 0, 0);
    o0 = __builtin_amdgcn_mfma_f32_32x32x16_bf16(ap1, h01, o0, 0, 0, 0);
    o1 = __builtin_amdgcn_mfma_f32_32x32x16_bf16(ap0, h10, o1, 0, 0, 0);
    o1 = __builtin_amdgcn_mfma_f32_32x32x16_bf16(ap1, h11, o1, 0, 0, 0);

    af0 = naf0; af1 = naf1;
    h00 = nh00; h01 = nh01; h10 = nh10; h11 = nh11;
  }

  // ---- split combine: sid1 hands O (bf16 pairs) + l to sid0 via LDS ----
  if (sid) {
    u32* dst = &ols[w & 3][lan][0];
#pragma unroll
    for (int r = 0; r < 16; ++r) dst[r] = pk2(o0[r], o1[r]);
    if ((w & 3) == 0) lsh[lan] = l_run;
  }
  __syncthreads();
  if (sid) return;

  const u32* src = &ols[w & 3][lan][0];
#pragma unroll
  for (int r = 0; r < 16; ++r) {
    u32 v = src[r];
    o0[r] += __builtin_bit_cast(float, v << 16);
    o1[r] += __builtin_bit_cast(float, v & 0xFFFF0000u);
  }
  const float l_tot = l_run + lsh[lan];

  // epilogue: y = gamma * O / l + x
  const float gi = gamma / l_tot;
#pragma unroll
  for (int r = 0; r < 16; ++r) {
    const int nl = (r & 3) + 8 * (r >> 2) + 4 * g2;     // query row of this acc reg
    const float gir = __shfl(gi, nl);
    const size_t row = (size_t)b * NSEQ + n0 + nl;
    const size_t i0 = row * CDIM + cw + lan31;
    out[i0]      = fmaf(gir, o0[r], x[i0]);
    out[i0 + 32] = fmaf(gir, o1[r], x[i0 + 32]);
  }
}

extern "C" void kernel_launch(void* const* d_in, const int* in_sizes, int n_in,
                              void* d_out, int out_size, void* d_ws, size_t ws_size,
                              hipStream_t stream) {
  const float* x     = (const float*)d_in[0];
  const float* Wf    = (const float*)d_in[1];
  const float* bf    = (const float*)d_in[2];
  const float* Wg    = (const float*)d_in[3];
  const float* bg    = (const float*)d_in[4];
  const float* Wh    = (const float*)d_in[5];
  const float* bh    = (const float*)d_in[6];
  const float* gamma = (const float*)d_in[7];
  float* out = (float*)d_out;

  // layout: hT first so prefetch overruns land in f/g (in-bounds)
  u16* hT_ws = (u16*)d_ws;                                   // 8 MB
  u16* f_ws  = hT_ws + (size_t)BATCH * CDIM * NSEQ;          // 1 MB
  u16* g_ws  = f_ws  + (size_t)BATCH * NSEQ * CQK;           // 1 MB

  hipLaunchKernelGGL(proj_kernel, dim3(1024), dim3(256), 0, stream,
                     x, Wf, bf, Wg, bg, Wh, bh, f_ws, g_ws, hT_ws);
  hipLaunchKernelGGL(attn_kernel, dim3(512), dim3(512), 0, stream,
                     x, gamma, f_ws, g_ws, hT_ws, out);
}

// Round 10
// 192.971 us; speedup vs baseline: 1.6682x; 1.0882x over previous
//
#include <hip/hip_runtime.h>
#include <hip/hip_bf16.h>

#define BATCH 4
#define NSEQ  4096
#define CDIM  256
#define CQK   32
#define L2E   1.44269504088896340736f

typedef short bf16x8 __attribute__((ext_vector_type(8)));   // 8 bf16 in 4 VGPRs
typedef float f32x16 __attribute__((ext_vector_type(16)));
typedef unsigned short u16;
typedef unsigned int   u32;
typedef unsigned int   u32x4 __attribute__((ext_vector_type(4)));

__device__ __forceinline__ u32 pk2(float lo, float hi) {    // v_cvt_pk_bf16_f32
  u16 a = __builtin_bit_cast(u16, __float2bfloat16(lo));
  u16 b = __builtin_bit_cast(u16, __float2bfloat16(hi));
  return (u32)a | ((u32)b << 16);
}
__device__ __forceinline__ bf16x8 ld8(const u16* p) {
  uint4 u = *(const uint4*)p;
  return __builtin_bit_cast(bf16x8, u);
}
// raw v_exp_f32 WITHOUT inline asm: builtin keeps the TRANS-op hazard visible to the
// compiler (inline-asm version caused stale-register reads -> absmax 2.69 fail, r9).
__device__ __forceinline__ float exp2_raw(float x) {
#if __has_builtin(__builtin_amdgcn_exp2f)
  return __builtin_amdgcn_exp2f(x);
#else
  return exp2f(x);
#endif
}

// ---------------- projection kernel: hT (bf16 [B][256][4096]), f,g (bf16 [B*N][32]) ------
// f is pre-scaled by log2(e) so attention can use exp2 directly.
__global__ __launch_bounds__(256) void proj_kernel(
    const float* __restrict__ x,
    const float* __restrict__ Wf, const float* __restrict__ bf,
    const float* __restrict__ Wg, const float* __restrict__ bg,
    const float* __restrict__ Wh, const float* __restrict__ bh,
    u16* __restrict__ f_ws, u16* __restrict__ g_ws, u16* __restrict__ hT_ws) {
  __shared__ float xs[16][260];                 // +4 pad: conflict-free strided reads
  const int tid  = threadIdx.x;
  const int row0 = blockIdx.x * 16;             // global row in [0,16384)

  { // stage 16 rows of x
    const int r = tid >> 4, j = tid & 15;
    const float4* xg = (const float4*)(x + ((size_t)row0 + r) * CDIM);
#pragma unroll
    for (int t = 0; t < 4; ++t)
      *(float4*)&xs[r][(j + t * 16) * 4] = xg[j + t * 16];
  }
  __syncthreads();

  { // f and g: thread (rr,c) does rows rr and rr+8, column c
    const int c = tid & 31, rr = tid >> 5;
    float af0 = bf[c], af1 = bf[c], ag0 = bg[c], ag1 = bg[c];
    for (int k = 0; k < CDIM; ++k) {
      float wf = Wf[k * CQK + c], wg = Wg[k * CQK + c];
      float x0 = xs[rr][k], x1 = xs[rr + 8][k];
      af0 = fmaf(x0, wf, af0); af1 = fmaf(x1, wf, af1);
      ag0 = fmaf(x0, wg, ag0); ag1 = fmaf(x1, wg, ag1);
    }
    f_ws[((size_t)row0 + rr)     * CQK + c] = (u16)(pk2(af0 * L2E, 0.f) & 0xFFFF);
    f_ws[((size_t)row0 + rr + 8) * CQK + c] = (u16)(pk2(af1 * L2E, 0.f) & 0xFFFF);
    g_ws[((size_t)row0 + rr)     * CQK + c] = (u16)(pk2(ag0, 0.f) & 0xFFFF);
    g_ws[((size_t)row0 + rr + 8) * CQK + c] = (u16)(pk2(ag1, 0.f) & 0xFFFF);
  }

  { // h: thread = output channel c; 16 rows; store transposed
    const int c = tid;
    float acc[16];
#pragma unroll
    for (int r = 0; r < 16; ++r) acc[r] = bh[c];
    for (int k = 0; k < CDIM; ++k) {
      float wk = Wh[k * CDIM + c];
#pragma unroll
      for (int r = 0; r < 16; ++r) acc[r] = fmaf(xs[r][k], wk, acc[r]);
    }
    const int b = row0 >> 12, n0 = row0 & (NSEQ - 1);
    u16* dst = hT_ws + ((size_t)b * CDIM + c) * NSEQ + n0;
    uint4 w0 = make_uint4(pk2(acc[0], acc[1]),  pk2(acc[2], acc[3]),
                          pk2(acc[4], acc[5]),  pk2(acc[6], acc[7]));
    uint4 w1 = make_uint4(pk2(acc[8], acc[9]),  pk2(acc[10], acc[11]),
                          pk2(acc[12], acc[13]), pk2(acc[14], acc[15]));
    *(uint4*)dst = w0;
    *(uint4*)(dst + 8) = w1;
  }
}

// ---------------- flash attention: waves partition KEYS (softmax computed ONCE) ---------
// Block = 32 queries, 4 waves; wave w owns keys [w*1024,(w+1)*1024), computes ALL 256
// channels (8 acc frags, 18 MFMA/chunk). No-max softmax => partials additive; one LDS
// combine round (bf16-packed), then per-wave epilogue on 64 channels.
// mfma_f32_32x32x16_bf16: A[row=l&31][k=(l>>5)*8+i], B[k=(l>>5)*8+i][col=l&31],
//   D[row=(r&3)+8*(r>>2)+4*(l>>5)][col=l&31]
__global__ __launch_bounds__(256, 2) void attn_kernel(
    const float* __restrict__ x, const float* __restrict__ gamma_p,
    const u16* __restrict__ f_ws, const u16* __restrict__ g_ws,
    const u16* __restrict__ hT_ws, float* __restrict__ out) {
  __shared__ u32   pls[4][64][64];              // 64KB partial-O exchange, lane-contiguous
  __shared__ float lsh[4][64];

  const int tid   = threadIdx.x;
  const int lan   = tid & 63;
  const int lan31 = lan & 31;
  const int g2    = lan >> 5;
  const int w     = tid >> 6;                   // wave id 0..3 (key-split)
  // XCD-aware swizzle: batch b pinned to XCDs {2b, 2b+1}
  const int bid   = blockIdx.x;
  const int xcd   = bid & 7;
  const int b     = xcd >> 1;
  const int n0    = (((xcd & 1) << 6) | (bid >> 3)) * 32;

  const float gamma = gamma_p[0];

  // query fragments (resident): B[k][n]=g[n][k]
  const u16* gp = g_ws + ((size_t)b * NSEQ + n0 + lan31) * CQK + g2 * 8;
  bf16x8 bg0 = ld8(gp);                         // k 0..15
  bf16x8 bg1 = ld8(gp + 16);                    // k 16..31

  f32x16 o[8], zfrag;
#pragma unroll
  for (int r = 0; r < 16; ++r) zfrag[r] = 0.f;
#pragma unroll
  for (int c = 0; c < 8; ++c) o[c] = zfrag;
  float l_run = 0.f;

  const u16* fbase = f_ws  + ((size_t)b * NSEQ + w * 1024 + lan31) * CQK + g2 * 8;
  const u16* hrow  = hT_ws + ((size_t)b * CDIM + lan31) * NSEQ + w * 1024 + g2 * 8;

  bf16x8 af0 = ld8(fbase), af1 = ld8(fbase + 16);
  const u16* fp = fbase + 32 * CQK;

  for (int it = 0; it < 32; ++it) {
    // S^T = f . g^T : lane holds 16 key-scores (log2 domain) for query col n
    f32x16 s = __builtin_amdgcn_mfma_f32_32x32x16_bf16(af0, bg0, zfrag, 0, 0, 0);
    s        = __builtin_amdgcn_mfma_f32_32x32x16_bf16(af1, bg1, s,     0, 0, 0);

    // prefetch next f chunk (w=3 overrun lands in g_ws; in-bounds)
    bf16x8 naf0 = ld8(fp), naf1 = ld8(fp + 16);
    fp += 32 * CQK;

    // p = exp2(s), raw TRANS op via builtin (hazard-safe)
    float p[16];
#pragma unroll
    for (int r = 0; r < 16; ++r) p[r] = exp2_raw(s[r]);

    float t0 = (p[0] + p[1]) + (p[2] + p[3]);
    float t1 = (p[4] + p[5]) + (p[6] + p[7]);
    float t2 = (p[8] + p[9]) + (p[10] + p[11]);
    float t3 = (p[12] + p[13]) + (p[14] + p[15]);
    float rs = (t0 + t1) + (t2 + t3);
    auto rr = __builtin_amdgcn_permlane32_swap(__builtin_bit_cast(u32, rs),
                                               __builtin_bit_cast(u32, rs), false, false);
    l_run += __builtin_bit_cast(float, (u32)rr[0]) + __builtin_bit_cast(float, (u32)rr[1]);

    // pack P quads: quad q holds keys m = 8q + 4*g2 .. +3
    u32 q0a = pk2(p[0],  p[1]),  q0b = pk2(p[2],  p[3]);
    u32 q1a = pk2(p[4],  p[5]),  q1b = pk2(p[6],  p[7]);
    u32 q2a = pk2(p[8],  p[9]),  q2b = pk2(p[10], p[11]);
    u32 q3a = pk2(p[12], p[13]), q3b = pk2(p[14], p[15]);

    auto r02a = __builtin_amdgcn_permlane32_swap(q0a, q1a, false, false);
    auto r13a = __builtin_amdgcn_permlane32_swap(q0b, q1b, false, false);
    auto r02b = __builtin_amdgcn_permlane32_swap(q2a, q3a, false, false);
    auto r13b = __builtin_amdgcn_permlane32_swap(q2b, q3b, false, false);
    u32x4 apu0 = {(u32)r02a[0], (u32)r13a[0], (u32)r02a[1], (u32)r13a[1]};
    u32x4 apu1 = {(u32)r02b[0], (u32)r13b[0], (u32)r02b[1], (u32)r13b[1]};
    bf16x8 ap0 = __builtin_bit_cast(bf16x8, apu0);
    bf16x8 ap1 = __builtin_bit_cast(bf16x8, apu1);

    // O[cg] += P . h  over all 8 channel groups (32 ch each)
    const u16* hp = hrow + it * 32;
#pragma unroll
    for (int cg = 0; cg < 8; ++cg) {
      bf16x8 ha = ld8(hp + (size_t)(cg * 32) * NSEQ);
      bf16x8 hb = ld8(hp + (size_t)(cg * 32) * NSEQ + 16);
      o[cg] = __builtin_amdgcn_mfma_f32_32x32x16_bf16(ap0, ha, o[cg], 0, 0, 0);
      o[cg] = __builtin_amdgcn_mfma_f32_32x32x16_bf16(ap1, hb, o[cg], 0, 0, 0);
    }

    af0 = naf0; af1 = naf1;
  }

  // ---- combine: all waves write bf16-packed partials; each wave sums one 64-ch slice ----
#pragma unroll
  for (int q = 0; q < 4; ++q)
#pragma unroll
    for (int r = 0; r < 16; ++r)
      pls[w][q * 16 + r][lan] = pk2(o[2 * q][r], o[2 * q + 1][r]);
  lsh[w][lan] = l_run;
  __syncthreads();

  float e0[16], e1[16];
#pragma unroll
  for (int r = 0; r < 16; ++r) { e0[r] = 0.f; e1[r] = 0.f; }
#pragma unroll
  for (int sgrp = 0; sgrp < 4; ++sgrp)
#pragma unroll
    for (int r = 0; r < 16; ++r) {
      u32 v = pls[sgrp][w * 16 + r][lan];
      e0[r] += __builtin_bit_cast(float, v << 16);
      e1[r] += __builtin_bit_cast(float, v & 0xFFFF0000u);
    }
  const float l_tot = lsh[0][lan] + lsh[1][lan] + lsh[2][lan] + lsh[3][lan];

  // epilogue: y = gamma * O / l + x ; wave w owns channels [w*64, w*64+64)
  const int cw = w * 64;
  const float gi = gamma / l_tot;
#pragma unroll
  for (int r = 0; r < 16; ++r) {
    const int nl = (r & 3) + 8 * (r >> 2) + 4 * g2;     // query row of this acc reg
    const float gir = __shfl(gi, nl);
    const size_t row = (size_t)b * NSEQ + n0 + nl;
    const size_t i0 = row * CDIM + cw + lan31;
    out[i0]      = fmaf(gir, e0[r], x[i0]);
    out[i0 + 32] = fmaf(gir, e1[r], x[i0 + 32]);
  }
}

extern "C" void kernel_launch(void* const* d_in, const int* in_sizes, int n_in,
                              void* d_out, int out_size, void* d_ws, size_t ws_size,
                              hipStream_t stream) {
  const float* x     = (const float*)d_in[0];
  const float* Wf    = (const float*)d_in[1];
  const float* bf    = (const float*)d_in[2];
  const float* Wg    = (const float*)d_in[3];
  const float* bg    = (const float*)d_in[4];
  const float* Wh    = (const float*)d_in[5];
  const float* bh    = (const float*)d_in[6];
  const float* gamma = (const float*)d_in[7];
  float* out = (float*)d_out;

  // layout: hT first so prefetch overruns land in f/g (in-bounds)
  u16* hT_ws = (u16*)d_ws;                                   // 8 MB
  u16* f_ws  = hT_ws + (size_t)BATCH * CDIM * NSEQ;          // 1 MB
  u16* g_ws  = f_ws  + (size_t)BATCH * NSEQ * CQK;           // 1 MB

  hipLaunchKernelGGL(proj_kernel, dim3(1024), dim3(256), 0, stream,
                     x, Wf, bf, Wg, bg, Wh, bh, f_ws, g_ws, hT_ws);
  hipLaunchKernelGGL(attn_kernel, dim3(512), dim3(256), 0, stream,
                     x, gamma, f_ws, g_ws, hT_ws, out);
}